// Round 9
// baseline (408.310 us; speedup 1.0000x reference)
//
#include <hip/hip_runtime.h>
#include <hip/hip_cooperative_groups.h>
#include <math.h>

namespace cg = cooperative_groups;

typedef __bf16 bf16_t;
typedef __bf16 bf16x8 __attribute__((ext_vector_type(8)));
typedef float f32x4 __attribute__((ext_vector_type(4)));

// Problem constants
#define M_ROWS 7680      // bs(4) * seq(32) * 60 patches
#define N1 512
#define K1 1024
#define NPX 160
#define NPY 96
#define BDIM 128         // bs*seq
#define NPATCH 60
#define NPIX (BDIM*NPX*NPY)

// ws float offsets
#define OFF_WGEFF   0                        // 512*3
#define OFF_BIASEFF 1536                     // 3 (pad to 2048)
#define OFF_CF      2048                     // 15360*3 = 46080
#define OFF_HW      48128                    // 7680*3  = 23040
#define OFF_HWPART  71168                    // 8*7680*3 = 184320
#define OFF_W1T     255488                   // bf16[512*1024] = 262144 floats

// GEMM tiling (r5/r6 measured-best structure)
#define BM 64
#define BN 64
#define BK 64
#define LDT 72           // padded LDS row (bf16): 144 B -> <=2-way banks (free)

static __device__ inline bf16x8 cvt8(float4 a, float4 b) {
    bf16x8 v;
    v[0] = (bf16_t)a.x; v[1] = (bf16_t)a.y; v[2] = (bf16_t)a.z; v[3] = (bf16_t)a.w;
    v[4] = (bf16_t)b.x; v[5] = (bf16_t)b.y; v[6] = (bf16_t)b.z; v[7] = (bf16_t)b.w;
    return v;
}

// ---------------------------------------------------------------------------
// Phase 0: blocks 0..127 transpose W1 -> W1T bf16; block 128 Wg_eff+bias_eff;
// blocks 129..308 coordinate field cf.
static __device__ void phase_prep(int bid, int t, char* smem,
    const float* __restrict__ W1, const float* __restrict__ W2,
    const float* __restrict__ b2, const float* __restrict__ Wg,
    const float* __restrict__ bg, float* __restrict__ ws)
{
    if (bid < 128) {
        bf16_t* tile = (bf16_t*)smem;          // [64][72]
        const int k0 = (bid & 15) * 64;
        const int n0 = (bid >> 4) * 64;
        bf16_t* W1T = (bf16_t*)(ws + OFF_W1T);
#pragma unroll
        for (int i = 0; i < 4; ++i) {
            int idx = t + i * 256;
            int r = idx >> 4, ch = idx & 15;
            float4 v = *(const float4*)(W1 + (size_t)(k0 + r) * N1 + n0 + ch * 4);
            bf16_t* dst = tile + r * 72 + ch * 4;
            dst[0] = (bf16_t)v.x; dst[1] = (bf16_t)v.y;
            dst[2] = (bf16_t)v.z; dst[3] = (bf16_t)v.w;
        }
        __syncthreads();
#pragma unroll
        for (int i = 0; i < 2; ++i) {
            int idx = t + i * 256;
            int nr = idx >> 3, kc = idx & 7;
            bf16x8 o;
#pragma unroll
            for (int j = 0; j < 8; ++j) o[j] = tile[(kc * 8 + j) * 72 + nr];
            *(bf16x8*)(W1T + (size_t)(n0 + nr) * K1 + k0 + kc * 8) = o;
        }
    } else if (bid == 128) {
#pragma unroll
        for (int rep = 0; rep < 2; ++rep) {
            int j = t + rep * 256;
            float a0 = 0.f, a1 = 0.f, a2 = 0.f;
            for (int k = 0; k < 128; ++k) {
                float w = W2[j * 128 + k];
                a0 = fmaf(w, Wg[k * 3 + 0], a0);
                a1 = fmaf(w, Wg[k * 3 + 1], a1);
                a2 = fmaf(w, Wg[k * 3 + 2], a2);
            }
            ws[OFF_WGEFF + j * 3 + 0] = a0;
            ws[OFF_WGEFF + j * 3 + 1] = a1;
            ws[OFF_WGEFF + j * 3 + 2] = a2;
        }
        if (t < 3) {
            float s = 0.f;
            for (int k = 0; k < 128; ++k) s = fmaf(b2[k], Wg[k * 3 + t], s);
            ws[OFF_BIASEFF + t] = s;
        }
    } else if (bid < 309) {
        int e = (bid - 129) * 256 + t;         // < 46080 exactly
        int c = e % 3;
        int p = e / 3;
        int x = p / NPY, y = p % NPY;
        float wpx = Wg[128 * 3 + c], wpy = Wg[129 * 3 + c];
        float wqx = Wg[130 * 3 + c], wqy = Wg[131 * 3 + c];
        auto aff = [&](int xx, int yy) -> float {
            return (float)(xx >> 4) * wpx + (float)(yy >> 4) * wpy
                 + (float)(xx & 15) * (1.f / 15.f) * wqx
                 + (float)(yy & 15) * (1.f / 15.f) * wqy;
        };
        auto deg = [&](int xx, int yy) -> float {
            return 1.f + (xx > 0) + (xx < NPX - 1) + (yy > 0) + (yy < NPY - 1);
        };
        float degc = deg(x, y);
        float s = 0.f;
        if (x > 0)       s += rsqrtf(deg(x - 1, y)) * aff(x - 1, y);
        if (x < NPX - 1) s += rsqrtf(deg(x + 1, y)) * aff(x + 1, y);
        if (y > 0)       s += rsqrtf(deg(x, y - 1)) * aff(x, y - 1);
        if (y < NPY - 1) s += rsqrtf(deg(x, y + 1)) * aff(x, y + 1);
        ws[OFF_CF + e] = rsqrtf(degc) * s + aff(x, y) / degc + bg[c];
    }
}

// ---------------------------------------------------------------------------
// Phase 1: MFMA GEMM (r5 measured-best body). 64x64 tile, BK=64, 960 blocks,
// bijective XCD chunk swizzle, 4 waves of 32x32 (2x2 frags of 16x16x32 bf16),
// double-buffered LDS for A and B.
static __device__ void phase_gemm(int bid, int t, char* smem,
    const float* __restrict__ A, const float* __restrict__ b1,
    float* __restrict__ ws)
{
    bf16_t* sA = (bf16_t*)smem;                  // [2][64][72]
    bf16_t* sB = sA + 2 * BM * LDT;              // [2][64][72]
    float* red = (float*)smem;                   // [64][32][3] (reused)
    const bf16_t* W1T = (const bf16_t*)(ws + OFF_W1T);

    // XCD chunk swizzle (bijective: 960 = 8 * 120)
    const int xcd = bid & 7;
    const int local = bid >> 3;                 // 0..119
    const int nblk = local & 7;                 // 0..7
    const int mblk = xcd * 15 + (local >> 3);   // 0..119
    const int m0 = mblk * BM;
    const int n0 = nblk * BN;

    const int lane = t & 63;
    const int wv = t >> 6;
    const int wr = wv >> 1, wc = wv & 1;
    const int l15 = lane & 15, hi = lane >> 4;

    const int srow = t >> 2;
    const int sq = (t & 3) << 4;
    const float*  aptr = A   + (size_t)(m0 + srow) * K1 + sq;
    const bf16_t* bptr = W1T + (size_t)(n0 + srow) * K1 + sq;
    const int swoff = srow * LDT + sq;

    f32x4 acc[2][2];
#pragma unroll
    for (int i = 0; i < 2; ++i)
#pragma unroll
        for (int j = 0; j < 2; ++j) acc[i][j] = (f32x4)0.f;

    {
        float4 fa0 = *(const float4*)(aptr + 0);
        float4 fa1 = *(const float4*)(aptr + 4);
        float4 fa2 = *(const float4*)(aptr + 8);
        float4 fa3 = *(const float4*)(aptr + 12);
        uint4  ub0 = *(const uint4*)(bptr);
        uint4  ub1 = *(const uint4*)(bptr + 8);
        *(bf16x8*)(sA + swoff)     = cvt8(fa0, fa1);
        *(bf16x8*)(sA + swoff + 8) = cvt8(fa2, fa3);
        *(uint4*)(sB + swoff)      = ub0;
        *(uint4*)(sB + swoff + 8)  = ub1;
    }
    __syncthreads();

    int cur = 0;
    for (int ks = 0; ks < K1 / BK; ++ks) {
        float4 fa0, fa1, fa2, fa3; uint4 ub0, ub1;
        const bool pf = (ks < K1 / BK - 1);
        if (pf) {
            const float*  ap = aptr + (ks + 1) * BK;
            const bf16_t* bp = bptr + (ks + 1) * BK;
            fa0 = *(const float4*)(ap + 0);
            fa1 = *(const float4*)(ap + 4);
            fa2 = *(const float4*)(ap + 8);
            fa3 = *(const float4*)(ap + 12);
            ub0 = *(const uint4*)(bp);
            ub1 = *(const uint4*)(bp + 8);
        }
        const bf16_t* cA = sA + cur * (BM * LDT);
        const bf16_t* cB = sB + cur * (BM * LDT);
        bf16x8 af[2][2], bfr[2][2];
#pragma unroll
        for (int i = 0; i < 2; ++i)
#pragma unroll
            for (int kk = 0; kk < 2; ++kk) {
                af[i][kk]  = *(const bf16x8*)(cA + (wr * 32 + i * 16 + l15) * LDT + kk * 32 + hi * 8);
                bfr[i][kk] = *(const bf16x8*)(cB + (wc * 32 + i * 16 + l15) * LDT + kk * 32 + hi * 8);
            }
#pragma unroll
        for (int kk = 0; kk < 2; ++kk)
#pragma unroll
            for (int mi = 0; mi < 2; ++mi)
#pragma unroll
                for (int ni = 0; ni < 2; ++ni)
                    acc[mi][ni] = __builtin_amdgcn_mfma_f32_16x16x32_bf16(
                        af[mi][kk], bfr[ni][kk], acc[mi][ni], 0, 0, 0);
        if (pf) {
            bf16_t* nA = sA + (cur ^ 1) * (BM * LDT);
            bf16_t* nB = sB + (cur ^ 1) * (BM * LDT);
            *(bf16x8*)(nA + swoff)     = cvt8(fa0, fa1);
            *(bf16x8*)(nA + swoff + 8) = cvt8(fa2, fa3);
            *(uint4*)(nB + swoff)      = ub0;
            *(uint4*)(nB + swoff + 8)  = ub1;
        }
        __syncthreads();
        cur ^= 1;
    }

    // epilogue: softplus + Wg_eff fold; per-lane partials -> LDS -> hw_part
    float b1v[2], wgv[2][3];
#pragma unroll
    for (int ni = 0; ni < 2; ++ni) {
        int n = n0 + wc * 32 + ni * 16 + l15;
        b1v[ni]    = b1[n];
        wgv[ni][0] = ws[OFF_WGEFF + n * 3 + 0];
        wgv[ni][1] = ws[OFF_WGEFF + n * 3 + 1];
        wgv[ni][2] = ws[OFF_WGEFF + n * 3 + 2];
    }
#pragma unroll
    for (int mi = 0; mi < 2; ++mi)
#pragma unroll
        for (int r = 0; r < 4; ++r) {
            float p0 = 0.f, p1 = 0.f, p2 = 0.f;
#pragma unroll
            for (int ni = 0; ni < 2; ++ni) {
                float z = acc[mi][ni][r] + b1v[ni];
                float sp = fmaxf(z, 0.f) + __logf(1.f + __expf(-fabsf(z)));
                p0 = fmaf(sp, wgv[ni][0], p0);
                p1 = fmaf(sp, wgv[ni][1], p1);
                p2 = fmaf(sp, wgv[ni][2], p2);
            }
            int ml = wr * 32 + mi * 16 + hi * 4 + r;   // 0..63 (bijective)
            int j  = wc * 16 + l15;                    // 0..31
            float* dst = red + (ml * 32 + j) * 3;
            dst[0] = p0; dst[1] = p1; dst[2] = p2;
        }
    __syncthreads();
    if (t < 192) {
        int m = t / 3, c = t - m * 3;
        float s = 0.f;
#pragma unroll
        for (int j = 0; j < 32; ++j) s += red[(m * 32 + j) * 3 + c];
        ws[OFF_HWPART + ((size_t)nblk * M_ROWS + m0 + m) * 3 + c] = s;
    }
}

// ---------------------------------------------------------------------------
// Phase 2: hw[p,c] = bias_eff[c] + sum_jb hw_part[jb][p][c]
static __device__ void phase_reduce(int bid, int t, float* __restrict__ ws)
{
    int idx = bid * 256 + t;
    if (idx >= M_ROWS * 3) return;
    int c = idx % 3;
    float s = ws[OFF_BIASEFF + c];
#pragma unroll
    for (int jb = 0; jb < 8; ++jb) s += ws[OFF_HWPART + jb * M_ROWS * 3 + idx];
    ws[OFF_HW + idx] = s;
}

// ---------------------------------------------------------------------------
// Phase 3: stencil, grid-stride over 4-pixel groups (3x float4 stores each).
static __device__ void phase_stencil(int bid, int t, int nthreads,
    const float* __restrict__ ws, float* __restrict__ out)
{
    const float* cf = ws + OFF_CF;
    auto deg = [&](int xx, int yy) -> float {
        return 1.f + (xx > 0) + (xx < NPX - 1) + (yy > 0) + (yy < NPY - 1);
    };
    for (int slot = bid * 256 + t; slot < NPIX / 4; slot += nthreads) {
        int p0 = slot * 4;
        int b = p0 / (NPX * NPY);
        int rem = p0 - b * (NPX * NPY);
        int x = rem / NPY, y0 = rem - x * NPY;     // y0 multiple of 4
        const float* hwb = ws + OFF_HW + b * NPATCH * 3;
        auto hwp = [&](int xx, int yy) -> const float* {
            return hwb + ((xx >> 4) * 6 + (yy >> 4)) * 3;
        };
        float res[4][3];
#pragma unroll
        for (int i = 0; i < 4; ++i) {
            int y = y0 + i;
            float degc = deg(x, y);
            float dinvc = rsqrtf(degc);
            float s0 = 0.f, s1 = 0.f, s2 = 0.f;
            auto tap = [&](int xx, int yy) {
                float dn = rsqrtf(deg(xx, yy));
                const float* h = hwp(xx, yy);
                s0 = fmaf(dn, h[0], s0);
                s1 = fmaf(dn, h[1], s1);
                s2 = fmaf(dn, h[2], s2);
            };
            if (x > 0)       tap(x - 1, y);
            if (x < NPX - 1) tap(x + 1, y);
            if (y > 0)       tap(x, y - 1);
            if (y < NPY - 1) tap(x, y + 1);
            const float* hs = hwp(x, y);
            const float* c = cf + (x * NPY + y) * 3;
            float inv_deg = 1.f / degc;
            res[i][0] = c[0] + fmaf(dinvc, s0, hs[0] * inv_deg);
            res[i][1] = c[1] + fmaf(dinvc, s1, hs[1] * inv_deg);
            res[i][2] = c[2] + fmaf(dinvc, s2, hs[2] * inv_deg);
        }
        float4 v0 = {res[0][0], res[0][1], res[0][2], res[1][0]};
        float4 v1 = {res[1][1], res[1][2], res[2][0], res[2][1]};
        float4 v2 = {res[2][2], res[3][0], res[3][1], res[3][2]};
        float* o = out + (size_t)p0 * 3;
        *(float4*)(o + 0) = v0;
        *(float4*)(o + 4) = v1;
        *(float4*)(o + 8) = v2;
    }
}

// ---------------------------------------------------------------------------
// mode 0: all phases with grid.sync (cooperative launch, 960 blocks).
// mode 1..4: single phase (ordered-launch fallback).
__global__ __launch_bounds__(256, 4) void mega_kernel(
    const float* __restrict__ A, const float* __restrict__ W1,
    const float* __restrict__ b1, const float* __restrict__ W2,
    const float* __restrict__ b2, const float* __restrict__ Wg,
    const float* __restrict__ bg, float* __restrict__ ws,
    float* __restrict__ out, int mode)
{
    __shared__ __align__(16) char smem[36864];
    const int bid = blockIdx.x;
    const int t = threadIdx.x;
    const int nthreads = gridDim.x * 256;

    if (mode == 0) {
        cg::grid_group g = cg::this_grid();
        phase_prep(bid, t, smem, W1, W2, b2, Wg, bg, ws);
        g.sync();
        phase_gemm(bid, t, smem, A, b1, ws);
        g.sync();
        phase_reduce(bid, t, ws);
        g.sync();
        phase_stencil(bid, t, nthreads, ws, out);
    } else if (mode == 1) {
        phase_prep(bid, t, smem, W1, W2, b2, Wg, bg, ws);
    } else if (mode == 2) {
        phase_gemm(bid, t, smem, A, b1, ws);
    } else if (mode == 3) {
        phase_reduce(bid, t, ws);
    } else {
        phase_stencil(bid, t, nthreads, ws, out);
    }
}

// ---------------------------------------------------------------------------
extern "C" void kernel_launch(void* const* d_in, const int* in_sizes, int n_in,
                              void* d_out, int out_size, void* d_ws, size_t ws_size,
                              hipStream_t stream) {
    const float* pv = (const float*)d_in[0];
    const float* W1 = (const float*)d_in[1];
    const float* b1 = (const float*)d_in[2];
    const float* W2 = (const float*)d_in[3];
    const float* b2 = (const float*)d_in[4];
    const float* Wg = (const float*)d_in[5];
    const float* bg = (const float*)d_in[6];
    // d_in[7] = edge_index: fixed 4-neighbor grid, derived analytically

    float* ws = (float*)d_ws;
    float* out = (float*)d_out;

    int mode0 = 0;
    void* args[] = {(void*)&pv, (void*)&W1, (void*)&b1, (void*)&W2, (void*)&b2,
                    (void*)&Wg, (void*)&bg, (void*)&ws, (void*)&out, (void*)&mode0};
    hipError_t err = hipLaunchCooperativeKernel((const void*)mega_kernel,
                                                dim3(960), dim3(256), args, 0, stream);
    if (err != hipSuccess) {
        (void)hipGetLastError();   // clear sticky error, use ordered fallback
        hipLaunchKernelGGL(mega_kernel, dim3(309), dim3(256), 0, stream,
                           pv, W1, b1, W2, b2, Wg, bg, ws, out, 1);
        hipLaunchKernelGGL(mega_kernel, dim3(960), dim3(256), 0, stream,
                           pv, W1, b1, W2, b2, Wg, bg, ws, out, 2);
        hipLaunchKernelGGL(mega_kernel, dim3(90), dim3(256), 0, stream,
                           pv, W1, b1, W2, b2, Wg, bg, ws, out, 3);
        hipLaunchKernelGGL(mega_kernel, dim3(960), dim3(256), 0, stream,
                           pv, W1, b1, W2, b2, Wg, bg, ws, out, 4);
    }
}

// Round 10
// 55.170 us; speedup vs baseline: 7.4009x; 7.4009x over previous
//
#include <hip/hip_runtime.h>
#include <math.h>

typedef __bf16 bf16_t;
typedef __bf16 bf16x8 __attribute__((ext_vector_type(8)));
typedef float f32x4 __attribute__((ext_vector_type(4)));

// Problem constants
#define M_ROWS 7680      // bs(4) * seq(32) * 60 patches
#define N1 512
#define K1 1024
#define NPX 160
#define NPY 96
#define BDIM 128         // bs*seq
#define NPATCH 60
#define NPIX (BDIM*NPX*NPY)

// ws float offsets
#define OFF_WGEFF   0                        // 512*3
#define OFF_BIASEFF 1536                     // 3 (pad to 2048)
#define OFF_CF      2048                     // 15360*3 = 46080
#define OFF_HWPART  71168                    // 8*7680*3 = 184320
#define OFF_W1T     255488                   // bf16[512*1024] = 262144 floats

// GEMM tiling (r6 measured-best structure)
#define BM 64
#define BN 64
#define BK 64
#define LDT 72           // padded LDS row (bf16): 144 B -> <=2-way banks (free)

// ---------------------------------------------------------------------------
// Merged prep: blocks 0..127 transpose W1 -> W1T bf16; block 128 computes
// Wg_eff + bias_eff; blocks 129..308 compute the coordinate field cf.
__global__ __launch_bounds__(256) void prep_kernel(
    const float* __restrict__ W1, const float* __restrict__ W2,
    const float* __restrict__ b2, const float* __restrict__ Wg,
    const float* __restrict__ bg, float* __restrict__ ws)
{
    const int t = threadIdx.x;
    if (blockIdx.x < 128) {
        __shared__ bf16_t tile[64][72];
        const int k0 = (blockIdx.x & 15) * 64;
        const int n0 = (blockIdx.x >> 4) * 64;
        bf16_t* W1T = (bf16_t*)(ws + OFF_W1T);
#pragma unroll
        for (int i = 0; i < 4; ++i) {
            int idx = t + i * 256;
            int r = idx >> 4, ch = idx & 15;
            float4 v = *(const float4*)(W1 + (size_t)(k0 + r) * N1 + n0 + ch * 4);
            bf16_t* dst = &tile[r][ch * 4];
            dst[0] = (bf16_t)v.x; dst[1] = (bf16_t)v.y;
            dst[2] = (bf16_t)v.z; dst[3] = (bf16_t)v.w;
        }
        __syncthreads();
#pragma unroll
        for (int i = 0; i < 2; ++i) {
            int idx = t + i * 256;
            int nr = idx >> 3, kc = idx & 7;
            bf16x8 o;
#pragma unroll
            for (int j = 0; j < 8; ++j) o[j] = tile[kc * 8 + j][nr];
            *(bf16x8*)(W1T + (size_t)(n0 + nr) * K1 + k0 + kc * 8) = o;
        }
    } else if (blockIdx.x == 128) {
#pragma unroll
        for (int rep = 0; rep < 2; ++rep) {
            int j = t + rep * 256;
            float a0 = 0.f, a1 = 0.f, a2 = 0.f;
            for (int k = 0; k < 128; ++k) {
                float w = W2[j * 128 + k];
                a0 = fmaf(w, Wg[k * 3 + 0], a0);
                a1 = fmaf(w, Wg[k * 3 + 1], a1);
                a2 = fmaf(w, Wg[k * 3 + 2], a2);
            }
            ws[OFF_WGEFF + j * 3 + 0] = a0;
            ws[OFF_WGEFF + j * 3 + 1] = a1;
            ws[OFF_WGEFF + j * 3 + 2] = a2;
        }
        if (t < 3) {
            float s = 0.f;
            for (int k = 0; k < 128; ++k) s = fmaf(b2[k], Wg[k * 3 + t], s);
            ws[OFF_BIASEFF + t] = s;
        }
    } else {
        int e = (blockIdx.x - 129) * 256 + t;    // < 46080 exactly
        int c = e % 3;
        int p = e / 3;
        int x = p / NPY, y = p % NPY;
        float wpx = Wg[128 * 3 + c], wpy = Wg[129 * 3 + c];
        float wqx = Wg[130 * 3 + c], wqy = Wg[131 * 3 + c];
        auto aff = [&](int xx, int yy) -> float {
            return (float)(xx >> 4) * wpx + (float)(yy >> 4) * wpy
                 + (float)(xx & 15) * (1.f / 15.f) * wqx
                 + (float)(yy & 15) * (1.f / 15.f) * wqy;
        };
        auto deg = [&](int xx, int yy) -> float {
            return 1.f + (xx > 0) + (xx < NPX - 1) + (yy > 0) + (yy < NPY - 1);
        };
        float degc = deg(x, y);
        float s = 0.f;
        if (x > 0)       s += rsqrtf(deg(x - 1, y)) * aff(x - 1, y);
        if (x < NPX - 1) s += rsqrtf(deg(x + 1, y)) * aff(x + 1, y);
        if (y > 0)       s += rsqrtf(deg(x, y - 1)) * aff(x, y - 1);
        if (y < NPY - 1) s += rsqrtf(deg(x, y + 1)) * aff(x, y + 1);
        ws[OFF_CF + e] = rsqrtf(degc) * s + aff(x, y) / degc + bg[c];
    }
}

// ---------------------------------------------------------------------------
static __device__ inline bf16x8 cvt8(float4 a, float4 b) {
    bf16x8 v;
    v[0] = (bf16_t)a.x; v[1] = (bf16_t)a.y; v[2] = (bf16_t)a.z; v[3] = (bf16_t)a.w;
    v[4] = (bf16_t)b.x; v[5] = (bf16_t)b.y; v[6] = (bf16_t)b.z; v[7] = (bf16_t)b.w;
    return v;
}

// MFMA GEMM (r6 measured-best): 64x64 tile, BK=64, 960 blocks, XCD chunk
// swizzle, 512 threads = 8 waves (wave tile 32x16) -> ~30 waves/CU resident.
__global__ __launch_bounds__(512, 8) void gemm_mfma_kernel(
    const float* __restrict__ A,      // [7680,1024] f32
    const float* __restrict__ b1,     // [512]
    const float* __restrict__ ws,     // Wg_eff + W1T
    float* __restrict__ hw_part)      // [8][7680][3]
{
    __shared__ __align__(16) char smem[36864];
    bf16_t* sA = (bf16_t*)smem;                  // [2][64][72]
    bf16_t* sB = sA + 2 * BM * LDT;              // [2][64][72]
    float* red = (float*)smem;                   // [64][32][3] (reused)
    const bf16_t* W1T = (const bf16_t*)(ws + OFF_W1T);

    // XCD chunk swizzle (bijective: 960 = 8 * 120)
    const int bid = blockIdx.x;
    const int xcd = bid & 7;
    const int local = bid >> 3;                 // 0..119
    const int nblk = local & 7;                 // 0..7
    const int mblk = xcd * 15 + (local >> 3);   // 0..119
    const int m0 = mblk * BM;
    const int n0 = nblk * BN;

    const int t = threadIdx.x;
    const int lane = t & 63;
    const int wv = t >> 6;            // 0..7
    const int wr = wv & 1;            // m-half (32 rows)
    const int wcn = wv >> 1;          // n-quarter (16 cols)
    const int l15 = lane & 15, hi = lane >> 4;

    // staging: thread t -> row t>>3 (0..63), oct (t&7)*8 of the 64-k chunk
    const int srow = t >> 3;
    const int oct = (t & 7) << 3;
    const float*  aptr = A   + (size_t)(m0 + srow) * K1 + oct;
    const bf16_t* bptr = W1T + (size_t)(n0 + srow) * K1 + oct;
    const int swoff = srow * LDT + oct;

    f32x4 acc[2];
    acc[0] = (f32x4)0.f; acc[1] = (f32x4)0.f;

    // prologue: stage ks=0 into buffer 0
    {
        float4 fa0 = *(const float4*)(aptr + 0);
        float4 fa1 = *(const float4*)(aptr + 4);
        uint4  ub0 = *(const uint4*)(bptr);
        *(bf16x8*)(sA + swoff) = cvt8(fa0, fa1);
        *(uint4*)(sB + swoff)  = ub0;
    }
    __syncthreads();

    int cur = 0;
    for (int ks = 0; ks < K1 / BK; ++ks) {
        float4 fa0, fa1; uint4 ub0;
        const bool pf = (ks < K1 / BK - 1);
        if (pf) {
            const float*  ap = aptr + (ks + 1) * BK;
            const bf16_t* bp = bptr + (ks + 1) * BK;
            fa0 = *(const float4*)(ap + 0);
            fa1 = *(const float4*)(ap + 4);
            ub0 = *(const uint4*)(bp);
        }
        const bf16_t* cA = sA + cur * (BM * LDT);
        const bf16_t* cB = sB + cur * (BM * LDT);
        bf16x8 af[2][2], bfr[2];
#pragma unroll
        for (int kk = 0; kk < 2; ++kk) {
#pragma unroll
            for (int mi = 0; mi < 2; ++mi)
                af[mi][kk] = *(const bf16x8*)(cA + (wr * 32 + mi * 16 + l15) * LDT + kk * 32 + hi * 8);
            bfr[kk] = *(const bf16x8*)(cB + (wcn * 16 + l15) * LDT + kk * 32 + hi * 8);
        }
#pragma unroll
        for (int kk = 0; kk < 2; ++kk)
#pragma unroll
            for (int mi = 0; mi < 2; ++mi)
                acc[mi] = __builtin_amdgcn_mfma_f32_16x16x32_bf16(
                    af[mi][kk], bfr[kk], acc[mi], 0, 0, 0);
        if (pf) {
            bf16_t* nA = sA + (cur ^ 1) * (BM * LDT);
            bf16_t* nB = sB + (cur ^ 1) * (BM * LDT);
            *(bf16x8*)(nA + swoff) = cvt8(fa0, fa1);
            *(uint4*)(nB + swoff)  = ub0;
        }
        __syncthreads();
        cur ^= 1;
    }

    // epilogue: softplus + Wg_eff fold; 2 deterministic LDS rounds
    const int n = n0 + wcn * 16 + l15;
    const float bb = b1[n];
    const float wg0 = ws[OFF_WGEFF + n * 3 + 0];
    const float wg1 = ws[OFF_WGEFF + n * 3 + 1];
    const float wg2 = ws[OFF_WGEFF + n * 3 + 2];
    const int jslot = (wcn & 1) * 16 + l15;    // 0..31

    float p[2][4][3];
#pragma unroll
    for (int mi = 0; mi < 2; ++mi)
#pragma unroll
        for (int r = 0; r < 4; ++r) {
            float z = acc[mi][r] + bb;
            float sp = fmaxf(z, 0.f) + __logf(1.f + __expf(-fabsf(z)));
            p[mi][r][0] = sp * wg0;
            p[mi][r][1] = sp * wg1;
            p[mi][r][2] = sp * wg2;
        }
    __syncthreads();
    if (wcn < 2) {
#pragma unroll
        for (int mi = 0; mi < 2; ++mi)
#pragma unroll
            for (int r = 0; r < 4; ++r) {
                int ml = wr * 32 + mi * 16 + hi * 4 + r;
                float* dst = red + (ml * 32 + jslot) * 3;
                dst[0] = p[mi][r][0]; dst[1] = p[mi][r][1]; dst[2] = p[mi][r][2];
            }
    }
    __syncthreads();
    if (wcn >= 2) {
#pragma unroll
        for (int mi = 0; mi < 2; ++mi)
#pragma unroll
            for (int r = 0; r < 4; ++r) {
                int ml = wr * 32 + mi * 16 + hi * 4 + r;
                float* dst = red + (ml * 32 + jslot) * 3;
                dst[0] += p[mi][r][0]; dst[1] += p[mi][r][1]; dst[2] += p[mi][r][2];
            }
    }
    __syncthreads();
    if (t < 192) {
        int m = t / 3, c = t - m * 3;
        float s = 0.f;
#pragma unroll
        for (int j = 0; j < 32; ++j) s += red[(m * 32 + j) * 3 + c];
        hw_part[((size_t)nblk * M_ROWS + m0 + m) * 3 + c] = s;
    }
}

// ---------------------------------------------------------------------------
// Fused hw-reduce + GCN stencil (r8-validated). 1280 blocks x 384 threads;
// block = one 16-col x 96-row pixel slab of one frame b. First 54 threads
// reduce the 8 hw_part slices for the 3x6 patch neighborhood into LDS, then
// every thread writes 4 pixels (3x float4 stores).
__global__ __launch_bounds__(384) void stencil_kernel(
    const float* __restrict__ ws, float* __restrict__ out)
{
    __shared__ float hwl[3][6][3];   // [dxi][py][c]
    const int blk = blockIdx.x;      // 0..1279
    const int b = blk / 10;
    const int px0 = blk % 10;
    const int x0 = px0 * 16;
    const int t = threadIdx.x;

    if (t < 54) {
        int j = t / 3, c = t - (t / 3) * 3;
        int dxi = j / 6, py = j % 6;
        int px = px0 - 1 + dxi;
        float v = 0.f;
        if (px >= 0 && px < 10) {
            int m = b * NPATCH + px * 6 + py;
            v = ws[OFF_BIASEFF + c];
#pragma unroll
            for (int s = 0; s < 8; ++s)
                v += ws[OFF_HWPART + ((size_t)s * M_ROWS + m) * 3 + c];
        }
        hwl[dxi][py][c] = v;
    }
    __syncthreads();

    const int xr = t / 24;             // 0..15
    const int y0 = (t - xr * 24) * 4;  // 0..92, multiple of 4
    const int x = x0 + xr;
    const float* cf = ws + OFF_CF;

    auto deg = [&](int xx, int yy) -> float {
        return 1.f + (xx > 0) + (xx < NPX - 1) + (yy > 0) + (yy < NPY - 1);
    };
    auto hwp = [&](int xx, int yy) -> const float* {
        return &hwl[(xx >> 4) - (px0 - 1)][yy >> 4][0];
    };

    float res[4][3];
#pragma unroll
    for (int i = 0; i < 4; ++i) {
        int y = y0 + i;
        float degc = deg(x, y);
        float dinvc = rsqrtf(degc);
        float s0 = 0.f, s1 = 0.f, s2 = 0.f;
        auto tap = [&](int xx, int yy) {
            float dn = rsqrtf(deg(xx, yy));
            const float* h = hwp(xx, yy);
            s0 = fmaf(dn, h[0], s0);
            s1 = fmaf(dn, h[1], s1);
            s2 = fmaf(dn, h[2], s2);
        };
        if (x > 0)       tap(x - 1, y);
        if (x < NPX - 1) tap(x + 1, y);
        if (y > 0)       tap(x, y - 1);
        if (y < NPY - 1) tap(x, y + 1);
        const float* hs = hwp(x, y);
        const float* c = cf + (x * NPY + y) * 3;
        float inv_deg = 1.f / degc;
        res[i][0] = c[0] + fmaf(dinvc, s0, hs[0] * inv_deg);
        res[i][1] = c[1] + fmaf(dinvc, s1, hs[1] * inv_deg);
        res[i][2] = c[2] + fmaf(dinvc, s2, hs[2] * inv_deg);
    }
    float4 v0 = {res[0][0], res[0][1], res[0][2], res[1][0]};
    float4 v1 = {res[1][1], res[1][2], res[2][0], res[2][1]};
    float4 v2 = {res[2][2], res[3][0], res[3][1], res[3][2]};
    size_t p0 = ((size_t)b * NPX + x) * NPY + y0;
    float* o = out + p0 * 3;
    *(float4*)(o + 0) = v0;
    *(float4*)(o + 4) = v1;
    *(float4*)(o + 8) = v2;
}

// ---------------------------------------------------------------------------
extern "C" void kernel_launch(void* const* d_in, const int* in_sizes, int n_in,
                              void* d_out, int out_size, void* d_ws, size_t ws_size,
                              hipStream_t stream) {
    const float* pv = (const float*)d_in[0];
    const float* W1 = (const float*)d_in[1];
    const float* b1 = (const float*)d_in[2];
    const float* W2 = (const float*)d_in[3];
    const float* b2 = (const float*)d_in[4];
    const float* Wg = (const float*)d_in[5];
    const float* bg = (const float*)d_in[6];
    // d_in[7] = edge_index: fixed 4-neighbor grid, derived analytically

    float* ws = (float*)d_ws;
    float* out = (float*)d_out;

    hipLaunchKernelGGL(prep_kernel, dim3(309), dim3(256), 0, stream,
                       W1, W2, b2, Wg, bg, ws);
    hipLaunchKernelGGL(gemm_mfma_kernel, dim3(960), dim3(512), 0, stream,
                       pv, b1, ws, ws + OFF_HWPART);
    hipLaunchKernelGGL(stencil_kernel, dim3(1280), dim3(384), 0, stream,
                       ws, out);
}

// Round 11
// 52.082 us; speedup vs baseline: 7.8398x; 1.0593x over previous
//
#include <hip/hip_runtime.h>
#include <math.h>

typedef __bf16 bf16_t;
typedef __bf16 bf16x8 __attribute__((ext_vector_type(8)));
typedef float f32x4 __attribute__((ext_vector_type(4)));
typedef unsigned int u32;

// Problem constants
#define M_ROWS 7680      // bs(4) * seq(32) * 60 patches
#define N1 512
#define K1 1024
#define NPX 160
#define NPY 96
#define BDIM 128         // bs*seq
#define NPATCH 60
#define NPIX (BDIM*NPX*NPY)

// ws float offsets
#define OFF_WGEFF   0                        // 512*3
#define OFF_BIASEFF 1536                     // 3 (pad to 2048)
#define OFF_CF      2048                     // 15360*3 = 46080
#define OFF_HWPART  71168                    // 8*7680*3 = 184320
#define OFF_W1T     255488                   // bf16[512*1024] = 262144 float slots
#define OFF_ABF     517632                   // bf16[7680*1024] = 3932160 float slots
#define WS_NEED_BYTES ((size_t)OFF_ABF * 4 + (size_t)M_ROWS * K1 * 2)

// GEMM tiling
#define BM 64
#define BN 64
#define BK 64
#define LDT 72           // fallback path padded row

static __device__ __forceinline__ void gll16(const void* g, void* l) {
    __builtin_amdgcn_global_load_lds(
        (const __attribute__((address_space(1))) u32*)g,
        (__attribute__((address_space(3))) u32*)l, 16, 0, 0);
}

static __device__ inline bf16x8 cvt8(float4 a, float4 b) {
    bf16x8 v;
    v[0] = (bf16_t)a.x; v[1] = (bf16_t)a.y; v[2] = (bf16_t)a.z; v[3] = (bf16_t)a.w;
    v[4] = (bf16_t)b.x; v[5] = (bf16_t)b.y; v[6] = (bf16_t)b.z; v[7] = (bf16_t)b.w;
    return v;
}

// ---------------------------------------------------------------------------
// Merged prep: blocks 0..127 transpose W1 -> W1T bf16; block 128 Wg_eff +
// bias_eff; blocks 129..308 coordinate field cf; blocks 309..1268 (only
// launched on the big-ws path) convert A f32 -> Abf bf16 (8 rows/block).
__global__ __launch_bounds__(256) void prep_kernel(
    const float* __restrict__ A, const float* __restrict__ W1,
    const float* __restrict__ W2, const float* __restrict__ b2,
    const float* __restrict__ Wg, const float* __restrict__ bg,
    float* __restrict__ ws)
{
    const int t = threadIdx.x;
    if (blockIdx.x < 128) {
        __shared__ bf16_t tile[64][72];
        const int k0 = (blockIdx.x & 15) * 64;
        const int n0 = (blockIdx.x >> 4) * 64;
        bf16_t* W1T = (bf16_t*)(ws + OFF_W1T);
#pragma unroll
        for (int i = 0; i < 4; ++i) {
            int idx = t + i * 256;
            int r = idx >> 4, ch = idx & 15;
            float4 v = *(const float4*)(W1 + (size_t)(k0 + r) * N1 + n0 + ch * 4);
            bf16_t* dst = &tile[r][ch * 4];
            dst[0] = (bf16_t)v.x; dst[1] = (bf16_t)v.y;
            dst[2] = (bf16_t)v.z; dst[3] = (bf16_t)v.w;
        }
        __syncthreads();
#pragma unroll
        for (int i = 0; i < 2; ++i) {
            int idx = t + i * 256;
            int nr = idx >> 3, kc = idx & 7;
            bf16x8 o;
#pragma unroll
            for (int j = 0; j < 8; ++j) o[j] = tile[kc * 8 + j][nr];
            *(bf16x8*)(W1T + (size_t)(n0 + nr) * K1 + k0 + kc * 8) = o;
        }
    } else if (blockIdx.x == 128) {
#pragma unroll
        for (int rep = 0; rep < 2; ++rep) {
            int j = t + rep * 256;
            float a0 = 0.f, a1 = 0.f, a2 = 0.f;
            for (int k = 0; k < 128; ++k) {
                float w = W2[j * 128 + k];
                a0 = fmaf(w, Wg[k * 3 + 0], a0);
                a1 = fmaf(w, Wg[k * 3 + 1], a1);
                a2 = fmaf(w, Wg[k * 3 + 2], a2);
            }
            ws[OFF_WGEFF + j * 3 + 0] = a0;
            ws[OFF_WGEFF + j * 3 + 1] = a1;
            ws[OFF_WGEFF + j * 3 + 2] = a2;
        }
        if (t < 3) {
            float s = 0.f;
            for (int k = 0; k < 128; ++k) s = fmaf(b2[k], Wg[k * 3 + t], s);
            ws[OFF_BIASEFF + t] = s;
        }
    } else if (blockIdx.x < 309) {
        int e = (blockIdx.x - 129) * 256 + t;    // < 46080 exactly
        int c = e % 3;
        int p = e / 3;
        int x = p / NPY, y = p % NPY;
        float wpx = Wg[128 * 3 + c], wpy = Wg[129 * 3 + c];
        float wqx = Wg[130 * 3 + c], wqy = Wg[131 * 3 + c];
        auto aff = [&](int xx, int yy) -> float {
            return (float)(xx >> 4) * wpx + (float)(yy >> 4) * wpy
                 + (float)(xx & 15) * (1.f / 15.f) * wqx
                 + (float)(yy & 15) * (1.f / 15.f) * wqy;
        };
        auto deg = [&](int xx, int yy) -> float {
            return 1.f + (xx > 0) + (xx < NPX - 1) + (yy > 0) + (yy < NPY - 1);
        };
        float degc = deg(x, y);
        float s = 0.f;
        if (x > 0)       s += rsqrtf(deg(x - 1, y)) * aff(x - 1, y);
        if (x < NPX - 1) s += rsqrtf(deg(x + 1, y)) * aff(x + 1, y);
        if (y > 0)       s += rsqrtf(deg(x, y - 1)) * aff(x, y - 1);
        if (y < NPY - 1) s += rsqrtf(deg(x, y + 1)) * aff(x, y + 1);
        ws[OFF_CF + e] = rsqrtf(degc) * s + aff(x, y) / degc + bg[c];
    } else {
        // A f32 -> bf16 convert: block handles 8 rows = 1024 bf16x8 chunks
        bf16_t* Abf = (bf16_t*)(ws + OFF_ABF);
        const int m0 = (blockIdx.x - 309) * 8;
#pragma unroll
        for (int j = 0; j < 4; ++j) {
            int c = t + j * 256;                 // 0..1023
            int row = c >> 7;                    // 0..7
            int col8 = c & 127;                  // chunk of 8 elems
            const float* src = A + (size_t)(m0 + row) * K1 + col8 * 8;
            float4 v0 = *(const float4*)(src);
            float4 v1 = *(const float4*)(src + 4);
            *(bf16x8*)(Abf + (size_t)(m0 + row) * K1 + col8 * 8) = cvt8(v0, v1);
        }
    }
}

// ---------------------------------------------------------------------------
// NEW GEMM: both operands bf16, staged via global_load_lds width=16 into
// LINEAR [64][64] LDS tiles. 16-way read conflict of 128B rows is broken by
// the rule-#21 pair: inverse-swizzled SOURCE address (c16_src = p ^ (row&7))
// + the same XOR on the ds_read side. Zero ds_write, zero cvt in the K-loop.
// 960 blocks x 256 thr, 4 waves of 32x32, XCD chunk swizzle.
__global__ __launch_bounds__(256) void gemm_gll_kernel(
    const float* __restrict__ b1,     // [512]
    const float* __restrict__ ws,     // Wg_eff + W1T + Abf
    float* __restrict__ hw_part)      // [8][7680][3]
{
    __shared__ __align__(16) char smem[32768];
    bf16_t* sA = (bf16_t*)smem;                  // [2][64][64] bf16 = 16 KB
    bf16_t* sB = sA + 2 * 64 * 64;               // [2][64][64] bf16 = 16 KB
    float* red = (float*)smem;                   // [64][32][3] = 24 KB (reused)
    const bf16_t* W1T = (const bf16_t*)(ws + OFF_W1T);
    const bf16_t* Abf = (const bf16_t*)(ws + OFF_ABF);

    // XCD chunk swizzle (bijective: 960 = 8 * 120)
    const int bid = blockIdx.x;
    const int xcd = bid & 7;
    const int local = bid >> 3;                 // 0..119
    const int nblk = local & 7;                 // 0..7
    const int mblk = xcd * 15 + (local >> 3);   // 0..119
    const int m0 = mblk * BM;
    const int n0 = nblk * BN;

    const int t = threadIdx.x;
    const int lane = t & 63;
    const int wv = t >> 6;            // 0..3
    const int wr = wv >> 1, wc = wv & 1;
    const int l15 = lane & 15, hi = lane >> 4;
    const int x7 = l15 & 7;

    // staging (per wave, 2 gll instr per operand): instr i covers rows
    // 8*(2*wv+i) .. +8; lane l -> row +(l>>3), holds source chunk (l&7)^(l>>3)
    const int rbase0 = 8 * (2 * wv + 0) + (lane >> 3);
    const int c16src = (lane & 7) ^ (lane >> 3);
    const bf16_t* aSrc0 = Abf + (size_t)(m0 + rbase0) * K1 + c16src * 8;
    const bf16_t* aSrc1 = aSrc0 + (size_t)8 * K1;
    const bf16_t* bSrc0 = W1T + (size_t)(n0 + rbase0) * K1 + c16src * 8;
    const bf16_t* bSrc1 = bSrc0 + (size_t)8 * K1;
    // wave-uniform LDS bases (elems): instr i -> (2*wv+i)*512
    const int ldsOffA0 = (2 * wv + 0) * 512;
    const int ldsOffA1 = (2 * wv + 1) * 512;

    // fragment read offsets (elems within one [64][64] buffer), XOR-swizzled
    int aoff[2][2], boff[2][2];
#pragma unroll
    for (int mi = 0; mi < 2; ++mi)
#pragma unroll
        for (int kk = 0; kk < 2; ++kk) {
            aoff[mi][kk] = (wr * 32 + mi * 16 + l15) * 64 + ((kk * 4 + hi) ^ x7) * 8;
            boff[mi][kk] = (wc * 32 + mi * 16 + l15) * 64 + ((kk * 4 + hi) ^ x7) * 8;
        }

    f32x4 acc[2][2];
#pragma unroll
    for (int i = 0; i < 2; ++i)
#pragma unroll
        for (int j = 0; j < 2; ++j) acc[i][j] = (f32x4)0.f;

    // prologue: stage ks=0 into buffer 0
    gll16(aSrc0, sA + ldsOffA0);
    gll16(aSrc1, sA + ldsOffA1);
    gll16(bSrc0, sB + ldsOffA0);
    gll16(bSrc1, sB + ldsOffA1);
    __syncthreads();

    int cur = 0;
    for (int ks = 0; ks < K1 / BK; ++ks) {
        if (ks < K1 / BK - 1) {
            const int koff = (ks + 1) * BK;
            const int nb = (cur ^ 1) * 4096;
            gll16(aSrc0 + koff, sA + nb + ldsOffA0);
            gll16(aSrc1 + koff, sA + nb + ldsOffA1);
            gll16(bSrc0 + koff, sB + nb + ldsOffA0);
            gll16(bSrc1 + koff, sB + nb + ldsOffA1);
        }
        const bf16_t* cA = sA + cur * 4096;
        const bf16_t* cB = sB + cur * 4096;
        bf16x8 af[2][2], bfr[2][2];
#pragma unroll
        for (int i = 0; i < 2; ++i)
#pragma unroll
            for (int kk = 0; kk < 2; ++kk) {
                af[i][kk]  = *(const bf16x8*)(cA + aoff[i][kk]);
                bfr[i][kk] = *(const bf16x8*)(cB + boff[i][kk]);
            }
#pragma unroll
        for (int kk = 0; kk < 2; ++kk)
#pragma unroll
            for (int mi = 0; mi < 2; ++mi)
#pragma unroll
                for (int ni = 0; ni < 2; ++ni)
                    acc[mi][ni] = __builtin_amdgcn_mfma_f32_16x16x32_bf16(
                        af[mi][kk], bfr[ni][kk], acc[mi][ni], 0, 0, 0);
        __syncthreads();
        cur ^= 1;
    }

    // epilogue: softplus + Wg_eff fold; per-lane partials -> LDS -> hw_part
    float b1v[2], wgv[2][3];
#pragma unroll
    for (int ni = 0; ni < 2; ++ni) {
        int n = n0 + wc * 32 + ni * 16 + l15;
        b1v[ni]    = b1[n];
        wgv[ni][0] = ws[OFF_WGEFF + n * 3 + 0];
        wgv[ni][1] = ws[OFF_WGEFF + n * 3 + 1];
        wgv[ni][2] = ws[OFF_WGEFF + n * 3 + 2];
    }
#pragma unroll
    for (int mi = 0; mi < 2; ++mi)
#pragma unroll
        for (int r = 0; r < 4; ++r) {
            float p0 = 0.f, p1 = 0.f, p2 = 0.f;
#pragma unroll
            for (int ni = 0; ni < 2; ++ni) {
                float z = acc[mi][ni][r] + b1v[ni];
                float sp = fmaxf(z, 0.f) + __logf(1.f + __expf(-fabsf(z)));
                p0 = fmaf(sp, wgv[ni][0], p0);
                p1 = fmaf(sp, wgv[ni][1], p1);
                p2 = fmaf(sp, wgv[ni][2], p2);
            }
            int ml = wr * 32 + mi * 16 + hi * 4 + r;   // 0..63 (bijective)
            int j  = wc * 16 + l15;                    // 0..31
            float* dst = red + (ml * 32 + j) * 3;
            dst[0] = p0; dst[1] = p1; dst[2] = p2;
        }
    __syncthreads();
    if (t < 192) {
        int m = t / 3, c = t - m * 3;
        float s = 0.f;
#pragma unroll
        for (int j = 0; j < 32; ++j) s += red[(m * 32 + j) * 3 + c];
        hw_part[((size_t)nblk * M_ROWS + m0 + m) * 3 + c] = s;
    }
}

// ---------------------------------------------------------------------------
// FALLBACK GEMM (r10 verbatim): reg-staged, LDT=72 padded, 512 thr.
__global__ __launch_bounds__(512, 8) void gemm_mfma_kernel(
    const float* __restrict__ A, const float* __restrict__ b1,
    const float* __restrict__ ws, float* __restrict__ hw_part)
{
    __shared__ __align__(16) char smem[36864];
    bf16_t* sA = (bf16_t*)smem;
    bf16_t* sB = sA + 2 * BM * LDT;
    float* red = (float*)smem;
    const bf16_t* W1T = (const bf16_t*)(ws + OFF_W1T);

    const int bid = blockIdx.x;
    const int xcd = bid & 7;
    const int local = bid >> 3;
    const int nblk = local & 7;
    const int mblk = xcd * 15 + (local >> 3);
    const int m0 = mblk * BM;
    const int n0 = nblk * BN;

    const int t = threadIdx.x;
    const int lane = t & 63;
    const int wv = t >> 6;
    const int wr = wv & 1;
    const int wcn = wv >> 1;
    const int l15 = lane & 15, hi = lane >> 4;

    const int srow = t >> 3;
    const int oct = (t & 7) << 3;
    const float*  aptr = A   + (size_t)(m0 + srow) * K1 + oct;
    const bf16_t* bptr = W1T + (size_t)(n0 + srow) * K1 + oct;
    const int swoff = srow * LDT + oct;

    f32x4 acc[2];
    acc[0] = (f32x4)0.f; acc[1] = (f32x4)0.f;

    {
        float4 fa0 = *(const float4*)(aptr + 0);
        float4 fa1 = *(const float4*)(aptr + 4);
        uint4  ub0 = *(const uint4*)(bptr);
        *(bf16x8*)(sA + swoff) = cvt8(fa0, fa1);
        *(uint4*)(sB + swoff)  = ub0;
    }
    __syncthreads();

    int cur = 0;
    for (int ks = 0; ks < K1 / BK; ++ks) {
        float4 fa0, fa1; uint4 ub0;
        const bool pf = (ks < K1 / BK - 1);
        if (pf) {
            const float*  ap = aptr + (ks + 1) * BK;
            const bf16_t* bp = bptr + (ks + 1) * BK;
            fa0 = *(const float4*)(ap + 0);
            fa1 = *(const float4*)(ap + 4);
            ub0 = *(const uint4*)(bp);
        }
        const bf16_t* cA = sA + cur * (BM * LDT);
        const bf16_t* cB = sB + cur * (BM * LDT);
        bf16x8 af[2][2], bfr[2];
#pragma unroll
        for (int kk = 0; kk < 2; ++kk) {
#pragma unroll
            for (int mi = 0; mi < 2; ++mi)
                af[mi][kk] = *(const bf16x8*)(cA + (wr * 32 + mi * 16 + l15) * LDT + kk * 32 + hi * 8);
            bfr[kk] = *(const bf16x8*)(cB + (wcn * 16 + l15) * LDT + kk * 32 + hi * 8);
        }
#pragma unroll
        for (int kk = 0; kk < 2; ++kk)
#pragma unroll
            for (int mi = 0; mi < 2; ++mi)
                acc[mi] = __builtin_amdgcn_mfma_f32_16x16x32_bf16(
                    af[mi][kk], bfr[kk], acc[mi], 0, 0, 0);
        if (pf) {
            bf16_t* nA = sA + (cur ^ 1) * (BM * LDT);
            bf16_t* nB = sB + (cur ^ 1) * (BM * LDT);
            *(bf16x8*)(nA + swoff) = cvt8(fa0, fa1);
            *(uint4*)(nB + swoff)  = ub0;
        }
        __syncthreads();
        cur ^= 1;
    }

    const int n = n0 + wcn * 16 + l15;
    const float bb = b1[n];
    const float wg0 = ws[OFF_WGEFF + n * 3 + 0];
    const float wg1 = ws[OFF_WGEFF + n * 3 + 1];
    const float wg2 = ws[OFF_WGEFF + n * 3 + 2];
    const int jslot = (wcn & 1) * 16 + l15;

    float p[2][4][3];
#pragma unroll
    for (int mi = 0; mi < 2; ++mi)
#pragma unroll
        for (int r = 0; r < 4; ++r) {
            float z = acc[mi][r] + bb;
            float sp = fmaxf(z, 0.f) + __logf(1.f + __expf(-fabsf(z)));
            p[mi][r][0] = sp * wg0;
            p[mi][r][1] = sp * wg1;
            p[mi][r][2] = sp * wg2;
        }
    __syncthreads();
    if (wcn < 2) {
#pragma unroll
        for (int mi = 0; mi < 2; ++mi)
#pragma unroll
            for (int r = 0; r < 4; ++r) {
                int ml = wr * 32 + mi * 16 + hi * 4 + r;
                float* dst = red + (ml * 32 + jslot) * 3;
                dst[0] = p[mi][r][0]; dst[1] = p[mi][r][1]; dst[2] = p[mi][r][2];
            }
    }
    __syncthreads();
    if (wcn >= 2) {
#pragma unroll
        for (int mi = 0; mi < 2; ++mi)
#pragma unroll
            for (int r = 0; r < 4; ++r) {
                int ml = wr * 32 + mi * 16 + hi * 4 + r;
                float* dst = red + (ml * 32 + jslot) * 3;
                dst[0] += p[mi][r][0]; dst[1] += p[mi][r][1]; dst[2] += p[mi][r][2];
            }
    }
    __syncthreads();
    if (t < 192) {
        int m = t / 3, c = t - m * 3;
        float s = 0.f;
#pragma unroll
        for (int j = 0; j < 32; ++j) s += red[(m * 32 + j) * 3 + c];
        hw_part[((size_t)nblk * M_ROWS + m0 + m) * 3 + c] = s;
    }
}

// ---------------------------------------------------------------------------
// Fused hw-reduce + GCN stencil (r8/r10-validated).
__global__ __launch_bounds__(384) void stencil_kernel(
    const float* __restrict__ ws, float* __restrict__ out)
{
    __shared__ float hwl[3][6][3];
    const int blk = blockIdx.x;
    const int b = blk / 10;
    const int px0 = blk % 10;
    const int x0 = px0 * 16;
    const int t = threadIdx.x;

    if (t < 54) {
        int j = t / 3, c = t - (t / 3) * 3;
        int dxi = j / 6, py = j % 6;
        int px = px0 - 1 + dxi;
        float v = 0.f;
        if (px >= 0 && px < 10) {
            int m = b * NPATCH + px * 6 + py;
            v = ws[OFF_BIASEFF + c];
#pragma unroll
            for (int s = 0; s < 8; ++s)
                v += ws[OFF_HWPART + ((size_t)s * M_ROWS + m) * 3 + c];
        }
        hwl[dxi][py][c] = v;
    }
    __syncthreads();

    const int xr = t / 24;
    const int y0 = (t - xr * 24) * 4;
    const int x = x0 + xr;
    const float* cf = ws + OFF_CF;

    auto deg = [&](int xx, int yy) -> float {
        return 1.f + (xx > 0) + (xx < NPX - 1) + (yy > 0) + (yy < NPY - 1);
    };
    auto hwp = [&](int xx, int yy) -> const float* {
        return &hwl[(xx >> 4) - (px0 - 1)][yy >> 4][0];
    };

    float res[4][3];
#pragma unroll
    for (int i = 0; i < 4; ++i) {
        int y = y0 + i;
        float degc = deg(x, y);
        float dinvc = rsqrtf(degc);
        float s0 = 0.f, s1 = 0.f, s2 = 0.f;
        auto tap = [&](int xx, int yy) {
            float dn = rsqrtf(deg(xx, yy));
            const float* h = hwp(xx, yy);
            s0 = fmaf(dn, h[0], s0);
            s1 = fmaf(dn, h[1], s1);
            s2 = fmaf(dn, h[2], s2);
        };
        if (x > 0)       tap(x - 1, y);
        if (x < NPX - 1) tap(x + 1, y);
        if (y > 0)       tap(x, y - 1);
        if (y < NPY - 1) tap(x, y + 1);
        const float* hs = hwp(x, y);
        const float* c = cf + (x * NPY + y) * 3;
        float inv_deg = 1.f / degc;
        res[i][0] = c[0] + fmaf(dinvc, s0, hs[0] * inv_deg);
        res[i][1] = c[1] + fmaf(dinvc, s1, hs[1] * inv_deg);
        res[i][2] = c[2] + fmaf(dinvc, s2, hs[2] * inv_deg);
    }
    float4 v0 = {res[0][0], res[0][1], res[0][2], res[1][0]};
    float4 v1 = {res[1][1], res[1][2], res[2][0], res[2][1]};
    float4 v2 = {res[2][2], res[3][0], res[3][1], res[3][2]};
    size_t p0 = ((size_t)b * NPX + x) * NPY + y0;
    float* o = out + p0 * 3;
    *(float4*)(o + 0) = v0;
    *(float4*)(o + 4) = v1;
    *(float4*)(o + 8) = v2;
}

// ---------------------------------------------------------------------------
extern "C" void kernel_launch(void* const* d_in, const int* in_sizes, int n_in,
                              void* d_out, int out_size, void* d_ws, size_t ws_size,
                              hipStream_t stream) {
    const float* pv = (const float*)d_in[0];
    const float* W1 = (const float*)d_in[1];
    const float* b1 = (const float*)d_in[2];
    const float* W2 = (const float*)d_in[3];
    const float* b2 = (const float*)d_in[4];
    const float* Wg = (const float*)d_in[5];
    const float* bg = (const float*)d_in[6];
    // d_in[7] = edge_index: fixed 4-neighbor grid, derived analytically

    float* ws = (float*)d_ws;
    float* out = (float*)d_out;
    const bool big = ws_size >= WS_NEED_BYTES;

    if (big) {
        hipLaunchKernelGGL(prep_kernel, dim3(309 + 960), dim3(256), 0, stream,
                           pv, W1, W2, b2, Wg, bg, ws);
        hipLaunchKernelGGL(gemm_gll_kernel, dim3(960), dim3(256), 0, stream,
                           b1, ws, ws + OFF_HWPART);
    } else {
        hipLaunchKernelGGL(prep_kernel, dim3(309), dim3(256), 0, stream,
                           pv, W1, W2, b2, Wg, bg, ws);
        hipLaunchKernelGGL(gemm_mfma_kernel, dim3(960), dim3(512), 0, stream,
                           pv, b1, ws, ws + OFF_HWPART);
    }
    hipLaunchKernelGGL(stencil_kernel, dim3(1280), dim3(384), 0, stream,
                       ws, out);
}